// Round 6
// baseline (713.839 us; speedup 1.0000x reference)
//
#include <hip/hip_runtime.h>

// Problem constants (from reference setup_inputs)
constexpr int N_POINTS = 2000000;
constexpr int C = 32;          // DIM_FEAT
constexpr int H = 1024;        // GRID_H
constexpr int W = 1024;        // GRID_W

// Spatial bins: 64x64 bins of 16x16 texels. One bin's texel footprint
// (17x17x128B ~ 37 KB) is L2-resident -> corner gathers become L2 hits.
constexpr int BIN_SHIFT = 4;                     // 16 texels per bin side
constexpr int BINS_X = W >> BIN_SHIFT;           // 64
constexpr int BINS_Y = H >> BIN_SHIFT;           // 64
constexpr int N_BINS = BINS_X * BINS_Y;          // 4096

// Native clang vector types — required by __builtin_nontemporal_*.
typedef float f32x4 __attribute__((ext_vector_type(4)));
typedef float f32x2 __attribute__((ext_vector_type(2)));

// ---------------------------------------------------------------------------
// Workspace layout (bytes from d_ws) — regions padded, NO overlap:
//   tp          [H*W*C] float     @ 0                      (128 MiB)
//   counts      [N_BINS] int      @ TP_BYTES               (16 KB used / 32 KB reserved)
//   binStart    [N_BINS+1] int    @ TP_BYTES + 32 KB       (16.004 KB used / 32 KB reserved)
//   cursor      [N_BINS] int      @ TP_BYTES + 64 KB       (16 KB used / 32 KB reserved)
//   sortedIdx   [N_POINTS] int    @ TP_BYTES + 96 KB       (8 MB)
//   sortedCoord [N_POINTS] f32x2  @ +8 MB after sortedIdx  (16 MB)
// ---------------------------------------------------------------------------
constexpr size_t TP_BYTES   = (size_t)H * W * C * sizeof(float);
constexpr size_t OFS_COUNTS = TP_BYTES;
constexpr size_t OFS_START  = TP_BYTES + 32768;
constexpr size_t OFS_CURSOR = TP_BYTES + 65536;
constexpr size_t OFS_SIDX   = TP_BYTES + 98304;
constexpr size_t OFS_SCOORD = OFS_SIDX + (size_t)N_POINTS * sizeof(int);
constexpr size_t WS_NEEDED  = OFS_SCOORD + (size_t)N_POINTS * 2 * sizeof(float);

__device__ __forceinline__ int point_bin(float x, float y)
{
    const float ix = (x + 1.0f) * 0.5f * (float)(W - 1);
    const float iy = (y + 1.0f) * 0.5f * (float)(H - 1);
    int bx = ((int)ix) >> BIN_SHIFT;     // ix >= 0 always (x in [-1,1])
    int by = ((int)iy) >> BIN_SHIFT;
    bx = max(0, min(bx, BINS_X - 1));
    by = max(0, min(by, BINS_Y - 1));
    return by * BINS_X + bx;
}

// ---------------------------------------------------------------------------
// Kernel 1: transpose params [C][H][W] -> [H][W][C]. float4 both sides;
// params read once -> non-temporal. Grid (W/64, H), block 256.
// ---------------------------------------------------------------------------
__global__ __launch_bounds__(256) void transpose_chw_hwc(
    const float* __restrict__ in, float* __restrict__ out)
{
    __shared__ float tile[64][C + 1];
    const int x0  = blockIdx.x * 64;
    const int y   = blockIdx.y;
    const int tid = threadIdx.x;

#pragma unroll
    for (int r = 0; r < 2; ++r) {
        const int idx = tid + 256 * r;      // 0..511
        const int c   = idx >> 4;           // 0..31
        const int xq  = idx & 15;           // 0..15
        const f32x4 v = __builtin_nontemporal_load(
            (const f32x4*)&in[(size_t)c * (H * W) + (size_t)y * W + x0 + xq * 4]);
        tile[xq * 4 + 0][c] = v.x;
        tile[xq * 4 + 1][c] = v.y;
        tile[xq * 4 + 2][c] = v.z;
        tile[xq * 4 + 3][c] = v.w;
    }
    __syncthreads();

#pragma unroll
    for (int r = 0; r < 2; ++r) {
        const int idx = tid + 256 * r;      // 0..511
        const int x   = idx >> 3;           // 0..63
        const int c4  = idx & 7;            // 0..7
        f32x4 v;
        v.x = tile[x][c4 * 4 + 0];
        v.y = tile[x][c4 * 4 + 1];
        v.z = tile[x][c4 * 4 + 2];
        v.w = tile[x][c4 * 4 + 3];
        *(f32x4*)&out[((size_t)y * W + x0 + x) * C + c4 * 4] = v;
    }
}

// ---------------------------------------------------------------------------
// Binning passes
// ---------------------------------------------------------------------------
__global__ __launch_bounds__(256) void zero_bins(int* __restrict__ counts)
{
    const int i = blockIdx.x * 256 + threadIdx.x;
    if (i < N_BINS) counts[i] = 0;
}

__global__ __launch_bounds__(256) void count_points(
    const float* __restrict__ coord, int* __restrict__ counts)
{
    const int stride = gridDim.x * 256;
    for (int n = blockIdx.x * 256 + threadIdx.x; n < N_POINTS; n += stride) {
        const f32x2 xy = ((const f32x2*)coord)[n];
        atomicAdd(&counts[point_bin(xy.x, xy.y)], 1);
    }
}

// Single block, 256 threads; each thread owns 16 consecutive bins.
__global__ __launch_bounds__(256) void scan_bins(
    const int* __restrict__ counts, int* __restrict__ binStart,
    int* __restrict__ cursor)
{
    __shared__ int part[256];
    const int t = threadIdx.x;
    int local[16];
    int sum = 0;
#pragma unroll
    for (int k = 0; k < 16; ++k) { local[k] = counts[t * 16 + k]; sum += local[k]; }
    part[t] = sum;
    __syncthreads();
    // inclusive Hillis-Steele scan over 256 partials
    for (int off = 1; off < 256; off <<= 1) {
        const int v = (t >= off) ? part[t - off] : 0;
        __syncthreads();
        part[t] += v;
        __syncthreads();
    }
    int run = part[t] - sum;                 // exclusive prefix for this thread
#pragma unroll
    for (int k = 0; k < 16; ++k) {
        const int b = t * 16 + k;
        binStart[b] = run;
        cursor[b]   = run;
        run += local[k];
    }
    if (t == 255) binStart[N_BINS] = run;    // = N_POINTS (own region, no alias)
}

__global__ __launch_bounds__(256) void scatter_points(
    const float* __restrict__ coord, int* __restrict__ cursor,
    int* __restrict__ sortedIdx, f32x2* __restrict__ sortedCoord)
{
    const int stride = gridDim.x * 256;
    for (int n = blockIdx.x * 256 + threadIdx.x; n < N_POINTS; n += stride) {
        const f32x2 xy = ((const f32x2*)coord)[n];
        int pos = atomicAdd(&cursor[point_bin(xy.x, xy.y)], 1);
        pos = max(0, min(pos, N_POINTS - 1));   // defensive: never OOB
        sortedIdx[pos]   = n;
        sortedCoord[pos] = xy;
    }
}

// ---------------------------------------------------------------------------
// Kernel 2: bilinear sample, one block per bin. 8 lanes per point; lane j
// handles channels [4j,4j+4). Corner reads are L2-local within the bin.
// Output stores scattered (original point order) -> non-temporal.
// ---------------------------------------------------------------------------
__global__ __launch_bounds__(256) void sample_binned(
    const f32x2* __restrict__ sortedCoord, const int* __restrict__ sortedIdx,
    const int* __restrict__ binStart, const float* __restrict__ tp,
    float* __restrict__ out)
{
    const int b     = blockIdx.x;
    const int start = binStart[b];
    const int end   = binStart[b + 1];
    const int tid   = threadIdx.x;
    const int j     = tid & 7;           // float4 slot
    const int off   = j * 4;

    for (int i = start + (tid >> 3); i < end; i += 32) {
        const f32x2 xy = sortedCoord[i];
        const int   n  = sortedIdx[i];
        if ((unsigned)n >= (unsigned)N_POINTS) continue;   // defensive: never OOB

        const float ix = (xy.x + 1.0f) * 0.5f * (float)(W - 1);
        const float iy = (xy.y + 1.0f) * 0.5f * (float)(H - 1);
        const float ix0f = floorf(ix), iy0f = floorf(iy);
        const float ix1f = ix0f + 1.0f, iy1f = iy0f + 1.0f;

        const float w_nw = (ix1f - ix) * (iy1f - iy);
        const float w_ne = (ix - ix0f) * (iy1f - iy);
        const float w_sw = (ix1f - ix) * (iy - iy0f);
        const float w_se = (ix - ix0f) * (iy - iy0f);

        const int x0 = (int)fminf(fmaxf(ix0f, 0.0f), (float)(W - 1));
        const int x1 = (int)fminf(fmaxf(ix1f, 0.0f), (float)(W - 1));
        const int y0 = (int)fminf(fmaxf(iy0f, 0.0f), (float)(H - 1));
        const int y1 = (int)fminf(fmaxf(iy1f, 0.0f), (float)(H - 1));

        const f32x4 vnw = *(const f32x4*)&tp[((size_t)(y0 * W + x0)) * C + off];
        const f32x4 vne = *(const f32x4*)&tp[((size_t)(y0 * W + x1)) * C + off];
        const f32x4 vsw = *(const f32x4*)&tp[((size_t)(y1 * W + x0)) * C + off];
        const f32x4 vse = *(const f32x4*)&tp[((size_t)(y1 * W + x1)) * C + off];

        const f32x4 r = vnw * w_nw + vne * w_ne + vsw * w_sw + vse * w_se;
        __builtin_nontemporal_store(r, (f32x4*)&out[(size_t)n * C + off]);
    }
}

// ---------------------------------------------------------------------------
// Fallbacks (smaller ws_size)
// ---------------------------------------------------------------------------
__global__ __launch_bounds__(256) void sample_hwc(
    const float* __restrict__ coord, const float* __restrict__ tp,
    float* __restrict__ out)
{
    const int tid = blockIdx.x * blockDim.x + threadIdx.x;
    const int n = tid >> 3;
    const int j = tid & 7;
    if (n >= N_POINTS) return;

    const f32x2 xy = ((const f32x2*)coord)[n];
    const float ix = (xy.x + 1.0f) * 0.5f * (float)(W - 1);
    const float iy = (xy.y + 1.0f) * 0.5f * (float)(H - 1);
    const float ix0f = floorf(ix), iy0f = floorf(iy);
    const float ix1f = ix0f + 1.0f, iy1f = iy0f + 1.0f;

    const float w_nw = (ix1f - ix) * (iy1f - iy);
    const float w_ne = (ix - ix0f) * (iy1f - iy);
    const float w_sw = (ix1f - ix) * (iy - iy0f);
    const float w_se = (ix - ix0f) * (iy - iy0f);

    const int x0 = (int)fminf(fmaxf(ix0f, 0.0f), (float)(W - 1));
    const int x1 = (int)fminf(fmaxf(ix1f, 0.0f), (float)(W - 1));
    const int y0 = (int)fminf(fmaxf(iy0f, 0.0f), (float)(H - 1));
    const int y1 = (int)fminf(fmaxf(iy1f, 0.0f), (float)(H - 1));

    const int off = j * 4;
    const f32x4 vnw = *(const f32x4*)&tp[((size_t)(y0 * W + x0)) * C + off];
    const f32x4 vne = *(const f32x4*)&tp[((size_t)(y0 * W + x1)) * C + off];
    const f32x4 vsw = *(const f32x4*)&tp[((size_t)(y1 * W + x0)) * C + off];
    const f32x4 vse = *(const f32x4*)&tp[((size_t)(y1 * W + x1)) * C + off];

    const f32x4 r = vnw * w_nw + vne * w_ne + vsw * w_sw + vse * w_se;
    __builtin_nontemporal_store(r, (f32x4*)&out[(size_t)n * C + off]);
}

__global__ __launch_bounds__(256) void sample_chw(
    const float* __restrict__ coord, const float* __restrict__ p,
    float* __restrict__ out)
{
    const int tid = blockIdx.x * blockDim.x + threadIdx.x;
    const int n = tid >> 5;
    const int c = tid & 31;
    if (n >= N_POINTS) return;

    const float2 xy = ((const float2*)coord)[n];
    const float ix = (xy.x + 1.0f) * 0.5f * (float)(W - 1);
    const float iy = (xy.y + 1.0f) * 0.5f * (float)(H - 1);
    const float ix0f = floorf(ix), iy0f = floorf(iy);
    const float ix1f = ix0f + 1.0f, iy1f = iy0f + 1.0f;

    const float w_nw = (ix1f - ix) * (iy1f - iy);
    const float w_ne = (ix - ix0f) * (iy1f - iy);
    const float w_sw = (ix1f - ix) * (iy - iy0f);
    const float w_se = (ix - ix0f) * (iy - iy0f);

    const int x0 = (int)fminf(fmaxf(ix0f, 0.0f), (float)(W - 1));
    const int x1 = (int)fminf(fmaxf(ix1f, 0.0f), (float)(W - 1));
    const int y0 = (int)fminf(fmaxf(iy0f, 0.0f), (float)(H - 1));
    const int y1 = (int)fminf(fmaxf(iy1f, 0.0f), (float)(H - 1));

    const size_t plane = (size_t)c * (H * W);
    const float vnw = p[plane + (size_t)y0 * W + x0];
    const float vne = p[plane + (size_t)y0 * W + x1];
    const float vsw = p[plane + (size_t)y1 * W + x0];
    const float vse = p[plane + (size_t)y1 * W + x1];

    out[(size_t)n * C + c] = vnw * w_nw + vne * w_ne + vsw * w_sw + vse * w_se;
}

extern "C" void kernel_launch(void* const* d_in, const int* in_sizes, int n_in,
                              void* d_out, int out_size, void* d_ws, size_t ws_size,
                              hipStream_t stream)
{
    const float* coord  = (const float*)d_in[0];   // [N, 2]
    const float* params = (const float*)d_in[1];   // [1, C, H, W]
    float* out = (float*)d_out;                    // [N, C]

    char* ws = (char*)d_ws;

    if (ws_size >= WS_NEEDED) {
        float* tp          = (float*)(ws);
        int*   counts      = (int*)(ws + OFS_COUNTS);
        int*   binStart    = (int*)(ws + OFS_START);
        int*   cursor      = (int*)(ws + OFS_CURSOR);
        int*   sortedIdx   = (int*)(ws + OFS_SIDX);
        f32x2* sortedCoord = (f32x2*)(ws + OFS_SCOORD);

        zero_bins<<<(N_BINS + 255) / 256, 256, 0, stream>>>(counts);
        dim3 tgrid(W / 64, H);
        transpose_chw_hwc<<<tgrid, 256, 0, stream>>>(params, tp);
        count_points<<<2048, 256, 0, stream>>>(coord, counts);
        scan_bins<<<1, 256, 0, stream>>>(counts, binStart, cursor);
        scatter_points<<<2048, 256, 0, stream>>>(coord, cursor, sortedIdx, sortedCoord);
        sample_binned<<<N_BINS, 256, 0, stream>>>(sortedCoord, sortedIdx, binStart, tp, out);
    } else if (ws_size >= TP_BYTES) {
        float* tp = (float*)ws;
        dim3 tgrid(W / 64, H);
        transpose_chw_hwc<<<tgrid, 256, 0, stream>>>(params, tp);
        const int blocks = (N_POINTS * 8 + 255) / 256;
        sample_hwc<<<blocks, 256, 0, stream>>>(coord, tp, out);
    } else {
        const int blocks = (N_POINTS * 32 + 255) / 256;
        sample_chw<<<blocks, 256, 0, stream>>>(coord, params, out);
    }
}